// Round 9
// baseline (281.871 us; speedup 1.0000x reference)
//
#include <hip/hip_runtime.h>
#include <hip/hip_bf16.h>
#include <math.h>

#define DD 128
#define QW2 1024     // row: 256 Q(pre-scaled) | 256 K | 256 V | 128 skip | 20 EQ | 108 pad
#define CAP 128
#define NB 125       // coarse buckets (dst>>7), 128 nodes each
#define BCAP 4096

typedef _Float16 f16x8 __attribute__((ext_vector_type(8)));
typedef _Float16 f16x2 __attribute__((ext_vector_type(2)));
typedef float f32x4 __attribute__((ext_vector_type(4)));

__device__ __forceinline__ float fdot2f(f16x2 a, f16x2 b, float c) {
#if __has_builtin(__builtin_amdgcn_fdot2)
  return __builtin_amdgcn_fdot2(a, b, c, false);
#else
  return fmaf((float)a[0], (float)b[0], fmaf((float)a[1], (float)b[1], c));
#endif
}

// ---------------- CSR build: two-level LDS counting sort (no memsets) ----------------
__global__ __launch_bounds__(256) void csr_count(const int* __restrict__ edst,
                                                 int* __restrict__ bparts, int E) {
  __shared__ int h[NB];
  const int tid = threadIdx.x;
  if (tid < NB) h[tid] = 0;
  __syncthreads();
  const int e0 = blockIdx.x * 2048;
  for (int k = 0; k < 8; ++k) {
    int e = e0 + k * 256 + tid;
    if (e < E) atomicAdd(&h[edst[e] >> 7], 1);
  }
  __syncthreads();
  if (tid < 128) bparts[blockIdx.x * 128 + tid] = (tid < NB) ? h[tid] : 0;
}

__global__ __launch_bounds__(128) void csr_scan(const int* __restrict__ bparts, int nblk,
                                                int* __restrict__ bbase,
                                                int* __restrict__ bcursor,
                                                int* __restrict__ offs, int E, int Nn) {
  __shared__ int sc[128];
  const int tid = threadIdx.x;
  int s = 0;
  for (int b = 0; b < nblk; ++b) s += bparts[b * 128 + tid];
  sc[tid] = (tid < NB) ? s : 0;
  __syncthreads();
  for (int d = 1; d < 128; d <<= 1) {
    int t = (tid >= d) ? sc[tid - d] : 0;
    __syncthreads();
    sc[tid] += t;
    __syncthreads();
  }
  const int excl = tid ? sc[tid - 1] : 0;
  if (tid < NB) { bbase[tid] = excl; bcursor[tid] = excl; }
  if (tid == 0) { bbase[NB] = E; offs[Nn] = E; }
}

__global__ __launch_bounds__(256) void csr_scatter(const int* __restrict__ edst,
                                                   const int* __restrict__ esrc,
                                                   const int* __restrict__ etyp,
                                                   int* __restrict__ bcursor,
                                                   unsigned* __restrict__ ebuf, int E) {
  __shared__ int h[NB], cur[NB];
  const int tid = threadIdx.x;
  if (tid < NB) h[tid] = 0;
  __syncthreads();
  const int e0 = blockIdx.x * 2048;
  int dd[8];
  for (int k = 0; k < 8; ++k) {
    int e = e0 + k * 256 + tid;
    dd[k] = (e < E) ? edst[e] : -1;
    if (dd[k] >= 0) atomicAdd(&h[dd[k] >> 7], 1);
  }
  __syncthreads();
  if (tid < NB && h[tid]) cur[tid] = atomicAdd(&bcursor[tid], h[tid]);
  __syncthreads();
  for (int k = 0; k < 8; ++k) {
    int e = e0 + k * 256 + tid;
    if (dd[k] >= 0) {
      int pos = atomicAdd(&cur[dd[k] >> 7], 1);
      ebuf[pos] = (unsigned)esrc[e] | ((unsigned)etyp[e] << 14) |
                  ((unsigned)(dd[k] & 127) << 18);
    }
  }
}

__global__ __launch_bounds__(256) void csr_fine(const unsigned* __restrict__ ebuf,
                                                const int* __restrict__ bbase,
                                                unsigned* __restrict__ epk,
                                                int* __restrict__ offs,
                                                int* __restrict__ dparts) {
  __shared__ unsigned sed[BCAP];
  __shared__ unsigned sout[BCAP];
  __shared__ int fh[128], sc[128], fc[128], hb[64];
  const int b = blockIdx.x, tid = threadIdx.x;
  const int base = bbase[b], cnt = bbase[b + 1] - base;
  for (int idx = tid; idx < cnt; idx += 256) sed[idx] = ebuf[base + idx];
  if (tid < 128) fh[tid] = 0;
  if (tid < 64) hb[tid] = 0;
  __syncthreads();
  for (int idx = tid; idx < cnt; idx += 256) atomicAdd(&fh[(sed[idx] >> 18) & 127], 1);
  __syncthreads();
  if (tid < 128) sc[tid] = fh[tid];
  __syncthreads();
  for (int d = 1; d < 128; d <<= 1) {
    int t = (tid < 128 && tid >= d) ? sc[tid - d] : 0;
    __syncthreads();
    if (tid < 128) sc[tid] += t;
    __syncthreads();
  }
  if (tid < 128) {
    const int excl = tid ? sc[tid - 1] : 0;
    offs[b * 128 + tid] = base + excl;
    fc[tid] = excl;
    atomicAdd(&hb[min(fh[tid], 63)], 1);
  }
  __syncthreads();
  if (tid < 64) dparts[b * 64 + tid] = hb[tid];
  for (int idx = tid; idx < cnt; idx += 256) {
    const unsigned v = sed[idx];
    const int pos = atomicAdd(&fc[(v >> 18) & 127], 1);
    sout[pos] = (v & 0x3FFF) | (((v >> 14) & 0xF) << 18);  // src | typ<<18
  }
  __syncthreads();
  for (int idx = tid; idx < cnt; idx += 256) epk[base + idx] = sout[idx];
}

__global__ __launch_bounds__(64) void deg_scan(const int* __restrict__ dparts, int nblk,
                                               int* __restrict__ dcur) {
  __shared__ int tot[64];
  const int t = threadIdx.x;
  int s = 0;
  for (int b = 0; b < nblk; ++b) s += dparts[b * 64 + t];
  tot[t] = s;
  __syncthreads();
  int acc = 0;
  for (int d = t + 1; d < 64; ++d) acc += tot[d];
  dcur[t] = acc;
}

__global__ __launch_bounds__(256) void deg_order(const int* __restrict__ offs,
                                                 int* __restrict__ dcur,
                                                 int* __restrict__ order, int Nn) {
  __shared__ int h[64], cbase[64];
  const int tid = threadIdx.x;
  const int i = blockIdx.x * 256 + tid;
  if (tid < 64) h[tid] = 0;
  __syncthreads();
  int bk = -1;
  if (i < Nn) {
    bk = min(offs[i + 1] - offs[i], 63);
    atomicAdd(&h[bk], 1);
  }
  __syncthreads();
  if (tid < 64) {
    const int c = h[tid];
    cbase[tid] = c ? atomicAdd(&dcur[tid], c) : 0;
    h[tid] = 0;
  }
  __syncthreads();
  if (bk >= 0) {
    const int pos = cbase[bk] + atomicAdd(&h[bk], 1);
    order[pos] = i;
  }
}

// ---------------- pp_cast: all parallel precompute + fw2 transpose tail blocks ------
__global__ __launch_bounds__(256) void pp_cast(
    const float* __restrict__ Wq, const float* __restrict__ Wk,
    const float* __restrict__ Wv, const float* __restrict__ Wsk,
    const float* __restrict__ bq, const float* __restrict__ bk,
    const float* __restrict__ bv, const float* __restrict__ bsk,
    const float* __restrict__ hemb, const float* __restrict__ We,
    const float* __restrict__ x,
    const float* __restrict__ fw1, const float* __restrict__ fb1,
    const float* __restrict__ fw2, const float* __restrict__ fb2,
    _Float16* __restrict__ WcatT, float* __restrict__ Wcat, float* __restrict__ bcat,
    _Float16* __restrict__ epth, float* __restrict__ eptf, _Float16* __restrict__ xh,
    _Float16* __restrict__ fw1h, _Float16* __restrict__ fw2Th,
    float* __restrict__ bfv, float* __restrict__ bzero, int Nn, int nb0) {
  __shared__ _Float16 tile[64][65];
  const float scale = 0.08838834764831845f;  // 1/sqrt(128)
  if (blockIdx.x >= nb0) {  // fw2 transpose+cast tail blocks (32 tiles)
    const int tb = blockIdx.x - nb0;
    const int l = tb >> 4, r2 = tb & 15;
    const int k0 = (r2 >> 1) << 6, j0 = (r2 & 1) << 6;
    const size_t base = (size_t)l * 65536;
    const int tid = threadIdx.x;
    for (int idx = tid; idx < 4096; idx += 256) {
      int rr = idx >> 6, cc = idx & 63;
      tile[rr][cc] = (_Float16)fw2[base + (size_t)(k0 + rr) * 128 + j0 + cc];
    }
    __syncthreads();
    for (int idx = tid; idx < 4096; idx += 256) {
      int rr = idx >> 6, cc = idx & 63;
      fw2Th[base + (size_t)(j0 + rr) * 512 + k0 + cc] = tile[cc][rr];
    }
    return;
  }
  int t = blockIdx.x * 256 + threadIdx.x;
  if (t < 256) {  // bfv[l][j]
    int l = t >> 7, j = t & 127;
    const float* b1 = fb1 + l * 512;
    const float* w2 = fw2 + (size_t)l * 65536 + j;
    float s0 = fb2[l * 128 + j], s1 = 0.f, s2 = 0.f, s3 = 0.f;
    for (int k = 0; k < 512; k += 4) {
      s0 = fmaf(b1[k], w2[(size_t)k * 128], s0);
      s1 = fmaf(b1[k + 1], w2[(size_t)(k + 1) * 128], s1);
      s2 = fmaf(b1[k + 2], w2[(size_t)(k + 2) * 128], s2);
      s3 = fmaf(b1[k + 3], w2[(size_t)(k + 3) * 128], s3);
    }
    bfv[t] = ((s0 + s1) + (s2 + s3));
    return;
  }
  t -= 256;
  if (t < 2560) {  // eproj (f16 + f32)
    int ty = t >> 8, col = t & 255;
    float s0 = 0.f, s1 = 0.f, s2 = 0.f, s3 = 0.f;
    const float* hr = hemb + ty * 128;
    for (int c = 0; c < 128; c += 4) {
      s0 = fmaf(hr[c], We[c * 256 + col], s0);
      s1 = fmaf(hr[c + 1], We[(c + 1) * 256 + col], s1);
      s2 = fmaf(hr[c + 2], We[(c + 2) * 256 + col], s2);
      s3 = fmaf(hr[c + 3], We[(c + 3) * 256 + col], s3);
    }
    const float v = ((s0 + s1) + (s2 + s3));
    epth[t] = (_Float16)v;
    eptf[t] = v;
    return;
  }
  t -= 2560;
  if (t < 131072) {  // WcatT f16 [1024][128] + Wcat f32 [128][1024]; Q rows pre-scaled
    int n = t >> 7, k = t & 127;
    float v;
    if (n < 256) v = scale * Wq[k * 256 + n];
    else if (n < 512) v = Wk[k * 256 + (n - 256)];
    else if (n < 768) v = Wv[k * 256 + (n - 512)];
    else if (n < 896) v = Wsk[k * 128 + (n - 768)];
    else v = 0.f;  // EQ cols overwritten by eq_cols; pad stays 0
    WcatT[t] = (_Float16)v;
    Wcat[k * 1024 + n] = v;
    return;
  }
  t -= 131072;
  if (t < 1024) {  // bcat (Q part pre-scaled; EQ part filled by eq_cols; pad 0)
    float v;
    if (t < 256) v = scale * bq[t];
    else if (t < 512) v = bk[t - 256];
    else if (t < 768) v = bv[t - 512];
    else if (t < 896) v = bsk[t - 768];
    else v = 0.f;
    bcat[t] = v;
    return;
  }
  t -= 1024;
  if (t < 1024) { bzero[t] = 0.f; return; }
  t -= 1024;
  if (t < 16384) {  // fw1 cast
    float4 v0 = *reinterpret_cast<const float4*>(fw1 + (size_t)t * 8);
    float4 v1 = *reinterpret_cast<const float4*>(fw1 + (size_t)t * 8 + 4);
    f16x8 o;
    o[0] = (_Float16)v0.x; o[1] = (_Float16)v0.y; o[2] = (_Float16)v0.z; o[3] = (_Float16)v0.w;
    o[4] = (_Float16)v1.x; o[5] = (_Float16)v1.y; o[6] = (_Float16)v1.z; o[7] = (_Float16)v1.w;
    *reinterpret_cast<f16x8*>(fw1h + (size_t)t * 8) = o;
    return;
  }
  t -= 16384;
  if (t < Nn * 16) {  // cast x -> f16
    float4 v0 = *reinterpret_cast<const float4*>(x + (size_t)t * 8);
    float4 v1 = *reinterpret_cast<const float4*>(x + (size_t)t * 8 + 4);
    f16x8 o;
    o[0] = (_Float16)v0.x; o[1] = (_Float16)v0.y; o[2] = (_Float16)v0.z; o[3] = (_Float16)v0.w;
    o[4] = (_Float16)v1.x; o[5] = (_Float16)v1.y; o[6] = (_Float16)v1.z; o[7] = (_Float16)v1.w;
    *reinterpret_cast<f16x8*>(xh + (size_t)t * 8) = o;
  }
}

// ---------------- eq_cols: Wcat/WcatT cols 896..915 = scaled Wq_h @ ept_ty_h ----------
__global__ __launch_bounds__(256) void eq_cols(float* __restrict__ Wcat,
                                               const float* __restrict__ eptf,
                                               float* __restrict__ bcat,
                                               _Float16* __restrict__ WcatT) {
  int t = blockIdx.x * 256 + threadIdx.x;
  if (t < 2560) {  // n in [0,20), k in [0,128)
    const int n = t >> 7, k = t & 127;
    const int h = n / 10, ty = n % 10;
    const float* wrow = Wcat + (size_t)k * 1024 + h * 128;  // pre-scaled Q slice
    const float* ep = eptf + ty * 256 + h * 128;
    float s0 = 0.f, s1 = 0.f, s2 = 0.f, s3 = 0.f;
    for (int c = 0; c < 128; c += 4) {
      s0 = fmaf(wrow[c], ep[c], s0);
      s1 = fmaf(wrow[c + 1], ep[c + 1], s1);
      s2 = fmaf(wrow[c + 2], ep[c + 2], s2);
      s3 = fmaf(wrow[c + 3], ep[c + 3], s3);
    }
    const float v = ((s0 + s1) + (s2 + s3));
    WcatT[(size_t)(896 + n) * 128 + k] = (_Float16)v;
    Wcat[(size_t)k * 1024 + 896 + n] = v;
    return;
  }
  t -= 2560;
  if (t < 20) {  // bias: bcat[896+n] = (scaled bq_h) . ept_ty_h
    const int h = t / 10, ty = t % 10;
    const float* ep = eptf + ty * 256 + h * 128;
    float s = 0.f;
    for (int c = 0; c < 128; ++c) s = fmaf(bcat[h * 128 + c], ep[c], s);
    bcat[896 + t] = s;
  }
}

// ---------------- pp_bmid: bmid = [bfv0 | bfv0@Wcat_ext + bcat_ext] (1152) ----------
__global__ __launch_bounds__(256) void pp_bmid(const float* __restrict__ bfv,
                                               const float* __restrict__ Wcat,
                                               const float* __restrict__ bcat,
                                               float* __restrict__ bmid) {
  int t = blockIdx.x * 256 + threadIdx.x;
  if (t >= 1152) return;
  if (t < 128) { bmid[t] = bfv[t]; return; }
  int n = t - 128;
  float s0 = bcat[n], s1 = 0.f, s2 = 0.f, s3 = 0.f;
  for (int c = 0; c < 128; c += 4) {
    s0 = fmaf(bfv[c], Wcat[c * 1024 + n], s0);
    s1 = fmaf(bfv[c + 1], Wcat[(c + 1) * 1024 + n], s1);
    s2 = fmaf(bfv[c + 2], Wcat[(c + 2) * 1024 + n], s2);
    s3 = fmaf(bfv[c + 3], Wcat[(c + 3) * 1024 + n], s3);
  }
  bmid[t] = ((s0 + s1) + (s2 + s3));
}

// ---------------- Wf[z] = fw1h[z] @ fw2Th[z]^T  (grid.z=2) -------------
__global__ __launch_bounds__(256) void wf_gemm(const _Float16* __restrict__ fw1h,
                                               const _Float16* __restrict__ fw2Th,
                                               float* __restrict__ Wf,
                                               _Float16* __restrict__ Wfh,
                                               _Float16* __restrict__ BtMid0) {
  const int z = blockIdx.z;
  const _Float16* A = fw1h + z * 65536;
  const _Float16* Bt = fw2Th + z * 65536;
  const int tid = threadIdx.x;
  const int wid = tid >> 6, lane = tid & 63;
  const int wr = wid >> 1, wc = wid & 1;
  const int il = lane & 15, g = lane >> 4;
  const int row0 = wr * 64, col0 = wc * 64;
  const _Float16* Ap = A + (size_t)(row0 + il) * 512 + 8 * g;
  const _Float16* Bp = Bt + (size_t)(col0 + il) * 512 + 8 * g;
  f32x4 acc[4][4];
#pragma unroll
  for (int a = 0; a < 4; ++a)
#pragma unroll
    for (int b = 0; b < 4; ++b) acc[a][b] = (f32x4){0.f, 0.f, 0.f, 0.f};
  for (int k0 = 0; k0 < 512; k0 += 32) {
    f16x8 af[4], bf[4];
#pragma unroll
    for (int f = 0; f < 4; ++f) {
      af[f] = *reinterpret_cast<const f16x8*>(Ap + (size_t)(f * 16) * 512 + k0);
      bf[f] = *reinterpret_cast<const f16x8*>(Bp + (size_t)(f * 16) * 512 + k0);
    }
#pragma unroll
    for (int fi = 0; fi < 4; ++fi)
#pragma unroll
      for (int fj = 0; fj < 4; ++fj)
        acc[fi][fj] = __builtin_amdgcn_mfma_f32_16x16x32_f16(af[fi], bf[fj], acc[fi][fj], 0, 0, 0);
  }
#pragma unroll
  for (int fj = 0; fj < 4; ++fj) {
    const int col = col0 + fj * 16 + il;
#pragma unroll
    for (int fi = 0; fi < 4; ++fi) {
#pragma unroll
      for (int i = 0; i < 4; ++i) {
        const int row = row0 + fi * 16 + g * 4 + i;
        const float v = acc[fi][fj][i];
        Wf[z * 16384 + row * 128 + col] = v;
        if (z == 0) {
          Wfh[row * 128 + col] = (_Float16)v;
          BtMid0[col * 128 + row] = (_Float16)v;
        }
      }
    }
  }
}

// ---------------- MFMA f16 GEMM: C = A[M,K] @ Bt[N,K]^T + bias ----------------
template <bool HAS_CFH, bool HAS_CH, bool HAS_CHT>
__global__ __launch_bounds__(256) void gemm_tn_f16(const _Float16* __restrict__ A,
                                                   const _Float16* __restrict__ Bt,
                                                   const float* __restrict__ bias,
                                                   _Float16* __restrict__ Cfh, int NF,
                                                   _Float16* __restrict__ Ch, int choff, int ldh,
                                                   _Float16* __restrict__ ChT, int ldt,
                                                   int M, int N, int K) {
  const int tid = threadIdx.x;
  const int wid = tid >> 6, lane = tid & 63;
  const int wr = wid >> 1, wc = wid & 1;
  const int il = lane & 15, g = lane >> 4;
  const int row0 = blockIdx.y * 128 + wr * 64;
  const int col0 = blockIdx.x * 128 + wc * 64;
  const _Float16* Ap = A + (size_t)(row0 + il) * K + 8 * g;
  const _Float16* Bp = Bt + (size_t)(col0 + il) * K + 8 * g;
  f32x4 acc[4][4];
#pragma unroll
  for (int a = 0; a < 4; ++a)
#pragma unroll
    for (int b = 0; b < 4; ++b) acc[a][b] = (f32x4){0.f, 0.f, 0.f, 0.f};
  for (int k0 = 0; k0 < K; k0 += 32) {
    f16x8 af[4], bf[4];
#pragma unroll
    for (int f = 0; f < 4; ++f) {
      af[f] = *reinterpret_cast<const f16x8*>(Ap + (size_t)(f * 16) * K + k0);
      bf[f] = *reinterpret_cast<const f16x8*>(Bp + (size_t)(f * 16) * K + k0);
    }
#pragma unroll
    for (int fi = 0; fi < 4; ++fi)
#pragma unroll
      for (int fj = 0; fj < 4; ++fj)
        acc[fi][fj] = __builtin_amdgcn_mfma_f32_16x16x32_f16(af[fi], bf[fj], acc[fi][fj], 0, 0, 0);
  }
#pragma unroll
  for (int fj = 0; fj < 4; ++fj) {
    const int col = col0 + fj * 16 + il;
    const float b = bias[col];
#pragma unroll
    for (int fi = 0; fi < 4; ++fi) {
#pragma unroll
      for (int i = 0; i < 4; ++i) {
        const int row = row0 + fi * 16 + g * 4 + i;
        const float v = acc[fi][fj][i] + b;
        if constexpr (HAS_CFH) { if (col < NF) Cfh[(size_t)row * NF + col] = (_Float16)v; }
        if constexpr (HAS_CH) { if (col >= choff) Ch[(size_t)row * ldh + (col - choff)] = (_Float16)v; }
        if constexpr (HAS_CHT) { ChT[(size_t)col * ldt + row] = (_Float16)v; }
      }
    }
  }
}

// ---------------- fused per-node attention + head-mean + skip + residual + LN -------
// Row layout (stride 1024): Q(pre-scaled) | K | V | skip | EQ[20] | pad.
// qe prologue is 20 scalar loads (EQ computed in the GEMM).
__global__ __launch_bounds__(256) void node_attn_ln_kernel(
    const _Float16* __restrict__ QKVSh, const _Float16* __restrict__ epth,
    const _Float16* __restrict__ hpre,
    const int* __restrict__ offs, const unsigned* __restrict__ epk,
    const int* __restrict__ order,
    const float* __restrict__ gamma, const float* __restrict__ beta,
    _Float16* __restrict__ hlnh, int Nn) {
  __shared__ float sl0[4][CAP], sl1[4][CAP];
  __shared__ unsigned spk[4][CAP];
  __shared__ float sqe[4][2][10];
  __shared__ __align__(16) _Float16 elds[2560];
  const int tid = threadIdx.x;
  for (int t = tid; t < 1280; t += 256)
    reinterpret_cast<unsigned*>(elds)[t] = reinterpret_cast<const unsigned*>(epth)[t];
  __syncthreads();
  const int w = tid >> 6, lane = tid & 63;
  const int i = order[blockIdx.x * 4 + w];
  const int sub = lane >> 5;
  const int r = lane & 31;
  const int half = r >> 4;
  const int co = r << 3;
  f16x8 qh = *reinterpret_cast<const f16x8*>(QKVSh + (size_t)i * QW2 + co);
  const f16x2* q2 = reinterpret_cast<const f16x2*>(&qh);
  if (lane < 20)
    sqe[w][lane / 10][lane % 10] = (float)QKVSh[(size_t)i * QW2 + 896 + lane];
  __threadfence_block();
  float m_me = -1e30f, s_me = 0.f;
  float acc[8] = {0.f};
  const int ebeg = offs[i], eend = offs[i + 1];
  for (int cs = ebeg; cs < eend; cs += CAP) {
    const int cnt = min(CAP, eend - cs);
    const int last = cnt - 1;
    for (int j = lane; j < cnt; j += 64) spk[w][j] = epk[cs + j];
    __threadfence_block();
    float cmax = -1e30f;
    {
      unsigned pk0 = spk[w][min(sub, last)];
      unsigned pk1 = spk[w][min(2 + sub, last)];
      f16x8 kv0 = *reinterpret_cast<const f16x8*>(QKVSh + (size_t)(pk0 & 0x3FFFF) * QW2 + 256 + co);
      f16x8 kv1 = *reinterpret_cast<const f16x8*>(QKVSh + (size_t)(pk1 & 0x3FFFF) * QW2 + 256 + co);
      int ty0 = pk0 >> 18, ty1 = pk1 >> 18;
      for (int j = 0; j < cnt; j += 2) {
        f16x8 kc = kv0;
        const int tyc = ty0;
        kv0 = kv1; ty0 = ty1;
        unsigned pkn = spk[w][min(j + 4 + sub, last)];
        ty1 = pkn >> 18;
        kv1 = *reinterpret_cast<const f16x8*>(QKVSh + (size_t)(pkn & 0x3FFFF) * QW2 + 256 + co);
        const f16x2* k2 = reinterpret_cast<const f16x2*>(&kc);
        float d = 0.f;
#pragma unroll
        for (int p2 = 0; p2 < 4; ++p2) d = fdot2f(q2[p2], k2[p2], d);
        d += __shfl_xor(d, 1); d += __shfl_xor(d, 2);
        d += __shfl_xor(d, 4); d += __shfl_xor(d, 8);
        d += sqe[w][half][tyc];
        if (j + sub < cnt) {
          cmax = fmaxf(cmax, d);
          if ((r & 15) == 0) (half ? sl1 : sl0)[w][j + sub] = d;
        }
      }
    }
    cmax = fmaxf(cmax, __shfl_xor(cmax, 32));
    const float nm = fmaxf(m_me, cmax);
    const float rr = __expf(m_me - nm);
    s_me *= rr;
#pragma unroll
    for (int t = 0; t < 8; ++t) acc[t] *= rr;
    m_me = nm;
    __threadfence_block();
    {
      unsigned pk0 = spk[w][min(sub, last)];
      unsigned pk1 = spk[w][min(2 + sub, last)];
      f16x8 vv0 = *reinterpret_cast<const f16x8*>(QKVSh + (size_t)(pk0 & 0x3FFFF) * QW2 + 512 + co);
      f16x8 ee0 = *reinterpret_cast<const f16x8*>(elds + ((pk0 >> 18) << 8) + co);
      f16x8 vv1 = *reinterpret_cast<const f16x8*>(QKVSh + (size_t)(pk1 & 0x3FFFF) * QW2 + 512 + co);
      f16x8 ee1 = *reinterpret_cast<const f16x8*>(elds + ((pk1 >> 18) << 8) + co);
      const float* slme = (half ? sl1 : sl0)[w];
      float ls = 0.f;
      for (int j = 0; j < cnt; j += 2) {
        f16x8 vc = vv0, ec = ee0;
        vv0 = vv1; ee0 = ee1;
        unsigned pkn = spk[w][min(j + 4 + sub, last)];
        vv1 = *reinterpret_cast<const f16x8*>(QKVSh + (size_t)(pkn & 0x3FFFF) * QW2 + 512 + co);
        ee1 = *reinterpret_cast<const f16x8*>(elds + ((pkn >> 18) << 8) + co);
        const int jc = j + sub;
        float e = 0.f;
        if (jc < cnt) e = __expf(slme[jc] - m_me);
        ls += e;
#pragma unroll
        for (int t = 0; t < 8; ++t) acc[t] = fmaf((float)vc[t] + (float)ec[t], e, acc[t]);
      }
      s_me += ls;
    }
  }
  const float s_tot = s_me + __shfl_xor(s_me, 32);
  const float invme = 1.f / (s_tot + 1e-16f);
  float g[8];
#pragma unroll
  for (int t = 0; t < 8; ++t) {
    float a = acc[t] + __shfl_xor(acc[t], 32);
    a *= invme;
    g[t] = 0.5f * (a + __shfl_xor(a, 16));
  }
  const int cm = (r & 15) << 3;
  f16x8 sk = *reinterpret_cast<const f16x8*>(QKVSh + (size_t)i * QW2 + 768 + cm);
  f16x8 pr = *reinterpret_cast<const f16x8*>(hpre + (size_t)i * DD + cm);
  float xv[8];
#pragma unroll
  for (int t = 0; t < 8; ++t) xv[t] = g[t] + (float)sk[t] + (float)pr[t];
  float sm = 0.f;
#pragma unroll
  for (int t = 0; t < 8; ++t) sm += xv[t];
  sm += __shfl_xor(sm, 1); sm += __shfl_xor(sm, 2);
  sm += __shfl_xor(sm, 4); sm += __shfl_xor(sm, 8);
  const float mu = sm * (1.f / 128.f);
  float dx[8], vvs = 0.f;
#pragma unroll
  for (int t = 0; t < 8; ++t) { dx[t] = xv[t] - mu; vvs += dx[t] * dx[t]; }
  vvs += __shfl_xor(vvs, 1); vvs += __shfl_xor(vvs, 2);
  vvs += __shfl_xor(vvs, 4); vvs += __shfl_xor(vvs, 8);
  const float rstd = rsqrtf(vvs * (1.f / 128.f) + 1e-6f);
  if (lane < 16) {
    float4 gm0 = *reinterpret_cast<const float4*>(gamma + cm);
    float4 gm1 = *reinterpret_cast<const float4*>(gamma + cm + 4);
    float4 bt0 = *reinterpret_cast<const float4*>(beta + cm);
    float4 bt1 = *reinterpret_cast<const float4*>(beta + cm + 4);
    f16x8 o;
    o[0] = (_Float16)(dx[0] * rstd * gm0.x + bt0.x);
    o[1] = (_Float16)(dx[1] * rstd * gm0.y + bt0.y);
    o[2] = (_Float16)(dx[2] * rstd * gm0.z + bt0.z);
    o[3] = (_Float16)(dx[3] * rstd * gm0.w + bt0.w);
    o[4] = (_Float16)(dx[4] * rstd * gm1.x + bt1.x);
    o[5] = (_Float16)(dx[5] * rstd * gm1.y + bt1.y);
    o[6] = (_Float16)(dx[6] * rstd * gm1.z + bt1.z);
    o[7] = (_Float16)(dx[7] * rstd * gm1.w + bt1.w);
    *reinterpret_cast<f16x8*>(hlnh + (size_t)i * DD + cm) = o;
  }
}

// ---------------- final: gather mask rows of hln1, apply layer-1 fused FFN ----------------
__global__ __launch_bounds__(128) void final_kernel(const _Float16* __restrict__ hlnh1,
                                                    const float* __restrict__ Wf,
                                                    const float* __restrict__ bfv,
                                                    const int* __restrict__ midx,
                                                    float* __restrict__ out) {
  __shared__ float rowv[128];
  const int b = blockIdx.x, j = threadIdx.x;
  const int row = midx[b];
  rowv[j] = (float)hlnh1[(size_t)row * DD + j];
  __syncthreads();
  const float* w1 = Wf + 16384 + j;
  float s = bfv[128 + j];
#pragma unroll 4
  for (int c = 0; c < 128; ++c) s = fmaf(rowv[c], w1[c * 128], s);
  out[b * DD + j] = s;
}

extern "C" void kernel_launch(void* const* d_in, const int* in_sizes, int n_in,
                              void* d_out, int out_size, void* d_ws, size_t ws_size,
                              hipStream_t stream) {
  const float* x    = (const float*)d_in[0];
  const float* hemb = (const float*)d_in[1];
  const float* Wq   = (const float*)d_in[2];
  const float* bq   = (const float*)d_in[3];
  const float* Wk   = (const float*)d_in[4];
  const float* bk   = (const float*)d_in[5];
  const float* Wv   = (const float*)d_in[6];
  const float* bv   = (const float*)d_in[7];
  const float* We   = (const float*)d_in[8];
  const float* Wsk  = (const float*)d_in[9];
  const float* bsk  = (const float*)d_in[10];
  const float* lng  = (const float*)d_in[11];
  const float* lnb  = (const float*)d_in[12];
  const float* fw1  = (const float*)d_in[13];
  const float* fb1  = (const float*)d_in[14];
  const float* fw2  = (const float*)d_in[15];
  const float* fb2  = (const float*)d_in[16];
  const int* eidx   = (const int*)d_in[17];
  const int* etyp   = (const int*)d_in[18];
  const int* midx   = (const int*)d_in[19];

  const int Nn = in_sizes[0] / DD;     // 16000
  const int E = in_sizes[18];          // 256000

  const int* esrc = eidx;
  const int* edst = eidx + E;

  char* p = (char*)d_ws;
  auto alloc = [&](size_t bytes) -> void* {
    void* r = (void*)p;
    p += (bytes + 255) & ~(size_t)255;
    return r;
  };
  _Float16* QKVSh = (_Float16*)alloc((size_t)Nn * QW2 * 2);
  _Float16* xh    = (_Float16*)alloc((size_t)Nn * DD * 2);
  _Float16* hln0  = (_Float16*)alloc((size_t)Nn * DD * 2);
  _Float16* hln1  = (_Float16*)alloc((size_t)Nn * DD * 2);
  _Float16* h1h   = (_Float16*)alloc((size_t)Nn * DD * 2);
  _Float16* WcatT = (_Float16*)alloc((size_t)1024 * DD * 2);
  float*    Wcat  = (float*)alloc((size_t)DD * 1024 * 4);
  float*    bcat  = (float*)alloc(1024 * 4);
  _Float16* epth  = (_Float16*)alloc(2560 * 2);
  float*    eptf  = (float*)alloc(2560 * 4);
  _Float16* fw1h  = (_Float16*)alloc((size_t)2 * DD * 512 * 2);
  _Float16* fw2Th = (_Float16*)alloc((size_t)2 * DD * 512 * 2);
  float*    Wf    = (float*)alloc(2 * 128 * 128 * 4);
  _Float16* Wfh   = (_Float16*)alloc(128 * 128 * 2);
  float*    bfv   = (float*)alloc(256 * 4);
  float*    bzero = (float*)alloc(1024 * 4);
  _Float16* BtMid = (_Float16*)alloc((size_t)1152 * 128 * 2);
  float*    bmid  = (float*)alloc(1152 * 4);
  int* offs   = (int*)alloc((size_t)(Nn + 1) * 4);
  int* bbase  = (int*)alloc((NB + 1) * 4);
  int* bcursor= (int*)alloc((NB + 1) * 4);
  int* dcur   = (int*)alloc(64 * 4);
  int* order  = (int*)alloc((size_t)Nn * 4);
  const int nsblk = (E + 2047) / 2048;
  int* bparts = (int*)alloc((size_t)nsblk * 128 * 4);
  int* dparts = (int*)alloc((size_t)NB * 64 * 4);
  unsigned* ebuf = (unsigned*)alloc((size_t)E * 4);
  unsigned* epk  = (unsigned*)alloc((size_t)E * 4);

  // CSR build (no memsets: partial histograms)
  csr_count<<<nsblk, 256, 0, stream>>>(edst, bparts, E);
  csr_scan<<<1, 128, 0, stream>>>(bparts, nsblk, bbase, bcursor, offs, E, Nn);
  csr_scatter<<<nsblk, 256, 0, stream>>>(edst, esrc, etyp, bcursor, ebuf, E);
  csr_fine<<<NB, 256, 0, stream>>>(ebuf, bbase, epk, offs, dparts);
  deg_scan<<<1, 64, 0, stream>>>(dparts, NB, dcur);
  deg_order<<<(Nn + 255) / 256, 256, 0, stream>>>(offs, dcur, order, Nn);

  // Precompute (pp_cast includes fw2 transpose tail blocks)
  const int pc_threads = 256 + 2560 + 131072 + 1024 + 1024 + 16384 + Nn * 16;
  const int nb0 = (pc_threads + 255) / 256;
  pp_cast<<<nb0 + 32, 256, 0, stream>>>(
      Wq, Wk, Wv, Wsk, bq, bk, bv, bsk, hemb, We, x, fw1, fb1, fw2, fb2,
      WcatT, Wcat, bcat, epth, eptf, xh, fw1h, fw2Th, bfv, bzero, Nn, nb0);
  eq_cols<<<11, 256, 0, stream>>>(Wcat, eptf, bcat, WcatT);
  wf_gemm<<<dim3(1, 1, 2), 256, 0, stream>>>(fw1h, fw2Th, Wf, Wfh, BtMid);
  pp_bmid<<<5, 256, 0, stream>>>(bfv, Wcat, bcat, bmid);
  // BtMid rows 128..1151 = (Wf0 @ Wcat_ext)^T
  gemm_tn_f16<false, false, true><<<dim3(8, 1), 256, 0, stream>>>(
      Wfh, WcatT, bzero, nullptr, 0, nullptr, 0, 0, BtMid + 16384, 128, 128, 1024, 128);

  // Layer 0: QKVS0(+EQ) = xh @ Wcat_ext + bcat_ext
  gemm_tn_f16<false, true, false><<<dim3(1024 / 128, Nn / 128), 256, 0, stream>>>(
      xh, WcatT, bcat, nullptr, 0, QKVSh, 0, QW2, nullptr, 0, Nn, 1024, DD);
  node_attn_ln_kernel<<<Nn / 4, 256, 0, stream>>>(QKVSh, epth, xh, offs, epk, order,
                                                  lng, lnb, hln0, Nn);
  // Fused: [h1h | QKVS1(+EQ)] = hln0 @ BtMid^T + bmid
  gemm_tn_f16<true, true, false><<<dim3(1152 / 128, Nn / 128), 256, 0, stream>>>(
      hln0, BtMid, bmid, h1h, 128, QKVSh, 128, QW2, nullptr, 0, Nn, 1152, DD);
  node_attn_ln_kernel<<<Nn / 4, 256, 0, stream>>>(QKVSh, epth, h1h, offs, epk, order,
                                                  lng + DD, lnb + DD, hln1, Nn);
  final_kernel<<<64, 128, 0, stream>>>(hln1, Wf, bfv, midx, (float*)d_out);
}

// Round 10
// 274.923 us; speedup vs baseline: 1.0253x; 1.0253x over previous
//
#include <hip/hip_runtime.h>
#include <hip/hip_bf16.h>
#include <math.h>

#define DD 128
#define QW 896       // 256(Q)+256(K)+256(V)+128(skip)
#define NB 125       // coarse buckets (dst>>7), 128 nodes each
#define BCAP 4096

typedef _Float16 f16x8 __attribute__((ext_vector_type(8)));
typedef _Float16 f16x2 __attribute__((ext_vector_type(2)));
typedef float f32x4 __attribute__((ext_vector_type(4)));

__device__ __forceinline__ float fdot2f(f16x2 a, f16x2 b, float c) {
#if __has_builtin(__builtin_amdgcn_fdot2)
  return __builtin_amdgcn_fdot2(a, b, c, false);
#else
  return fmaf((float)a[0], (float)b[0], fmaf((float)a[1], (float)b[1], c));
#endif
}

// ---------------- CSR build: two-level LDS counting sort (no memsets) ----------------
__global__ __launch_bounds__(256) void csr_count(const int* __restrict__ edst,
                                                 int* __restrict__ bparts, int E) {
  __shared__ int h[NB];
  const int tid = threadIdx.x;
  if (tid < NB) h[tid] = 0;
  __syncthreads();
  const int e0 = blockIdx.x * 2048;
  for (int k = 0; k < 8; ++k) {
    int e = e0 + k * 256 + tid;
    if (e < E) atomicAdd(&h[edst[e] >> 7], 1);
  }
  __syncthreads();
  if (tid < 128) bparts[blockIdx.x * 128 + tid] = (tid < NB) ? h[tid] : 0;
}

__global__ __launch_bounds__(128) void csr_scan(const int* __restrict__ bparts, int nblk,
                                                int* __restrict__ bbase,
                                                int* __restrict__ bcursor,
                                                int* __restrict__ offs, int E, int Nn) {
  __shared__ int sc[128];
  const int tid = threadIdx.x;
  int s = 0;
  for (int b = 0; b < nblk; ++b) s += bparts[b * 128 + tid];
  sc[tid] = (tid < NB) ? s : 0;
  __syncthreads();
  for (int d = 1; d < 128; d <<= 1) {
    int t = (tid >= d) ? sc[tid - d] : 0;
    __syncthreads();
    sc[tid] += t;
    __syncthreads();
  }
  const int excl = tid ? sc[tid - 1] : 0;
  if (tid < NB) { bbase[tid] = excl; bcursor[tid] = excl; }
  if (tid == 0) { bbase[NB] = E; offs[Nn] = E; }
}

__global__ __launch_bounds__(256) void csr_scatter(const int* __restrict__ edst,
                                                   const int* __restrict__ esrc,
                                                   const int* __restrict__ etyp,
                                                   int* __restrict__ bcursor,
                                                   unsigned* __restrict__ ebuf, int E) {
  __shared__ int h[NB], cur[NB];
  const int tid = threadIdx.x;
  if (tid < NB) h[tid] = 0;
  __syncthreads();
  const int e0 = blockIdx.x * 2048;
  int dd[8];
  for (int k = 0; k < 8; ++k) {
    int e = e0 + k * 256 + tid;
    dd[k] = (e < E) ? edst[e] : -1;
    if (dd[k] >= 0) atomicAdd(&h[dd[k] >> 7], 1);
  }
  __syncthreads();
  if (tid < NB && h[tid]) cur[tid] = atomicAdd(&bcursor[tid], h[tid]);
  __syncthreads();
  for (int k = 0; k < 8; ++k) {
    int e = e0 + k * 256 + tid;
    if (dd[k] >= 0) {
      int pos = atomicAdd(&cur[dd[k] >> 7], 1);
      ebuf[pos] = (unsigned)esrc[e] | ((unsigned)etyp[e] << 14) |
                  ((unsigned)(dd[k] & 127) << 18);
    }
  }
}

__global__ __launch_bounds__(256) void csr_fine(const unsigned* __restrict__ ebuf,
                                                const int* __restrict__ bbase,
                                                unsigned* __restrict__ epk,
                                                int* __restrict__ offs,
                                                int* __restrict__ dparts) {
  __shared__ unsigned sed[BCAP];
  __shared__ unsigned sout[BCAP];
  __shared__ int fh[128], sc[128], fc[128], hb[64];
  const int b = blockIdx.x, tid = threadIdx.x;
  const int base = bbase[b], cnt = bbase[b + 1] - base;
  for (int idx = tid; idx < cnt; idx += 256) sed[idx] = ebuf[base + idx];
  if (tid < 128) fh[tid] = 0;
  if (tid < 64) hb[tid] = 0;
  __syncthreads();
  for (int idx = tid; idx < cnt; idx += 256) atomicAdd(&fh[(sed[idx] >> 18) & 127], 1);
  __syncthreads();
  if (tid < 128) sc[tid] = fh[tid];
  __syncthreads();
  for (int d = 1; d < 128; d <<= 1) {
    int t = (tid < 128 && tid >= d) ? sc[tid - d] : 0;
    __syncthreads();
    if (tid < 128) sc[tid] += t;
    __syncthreads();
  }
  if (tid < 128) {
    const int excl = tid ? sc[tid - 1] : 0;
    offs[b * 128 + tid] = base + excl;
    fc[tid] = excl;
    atomicAdd(&hb[min(fh[tid], 63)], 1);
  }
  __syncthreads();
  if (tid < 64) dparts[b * 64 + tid] = hb[tid];
  for (int idx = tid; idx < cnt; idx += 256) {
    const unsigned v = sed[idx];
    const int pos = atomicAdd(&fc[(v >> 18) & 127], 1);
    sout[pos] = (v & 0x3FFF) | (((v >> 14) & 0xF) << 18);  // src | typ<<18
  }
  __syncthreads();
  for (int idx = tid; idx < cnt; idx += 256) epk[base + idx] = sout[idx];
}

__global__ __launch_bounds__(64) void deg_scan(const int* __restrict__ dparts, int nblk,
                                               int* __restrict__ dcur) {
  __shared__ int tot[64];
  const int t = threadIdx.x;
  int s = 0;
  for (int b = 0; b < nblk; ++b) s += dparts[b * 64 + t];
  tot[t] = s;
  __syncthreads();
  int acc = 0;
  for (int d = t + 1; d < 64; ++d) acc += tot[d];
  dcur[t] = acc;
}

__global__ __launch_bounds__(256) void deg_order(const int* __restrict__ offs,
                                                 int* __restrict__ dcur,
                                                 int* __restrict__ order, int Nn) {
  __shared__ int h[64], cbase[64];
  const int tid = threadIdx.x;
  const int i = blockIdx.x * 256 + tid;
  if (tid < 64) h[tid] = 0;
  __syncthreads();
  int bk = -1;
  if (i < Nn) {
    bk = min(offs[i + 1] - offs[i], 63);
    atomicAdd(&h[bk], 1);
  }
  __syncthreads();
  if (tid < 64) {
    const int c = h[tid];
    cbase[tid] = c ? atomicAdd(&dcur[tid], c) : 0;
    h[tid] = 0;
  }
  __syncthreads();
  if (bk >= 0) {
    const int pos = cbase[bk] + atomicAdd(&h[bk], 1);
    order[pos] = i;
  }
}

// ---------------- pp_cast: all parallel precompute + fw2 transpose tail blocks ------
__global__ __launch_bounds__(256) void pp_cast(
    const float* __restrict__ Wq, const float* __restrict__ Wk,
    const float* __restrict__ Wv, const float* __restrict__ Wsk,
    const float* __restrict__ bq, const float* __restrict__ bk,
    const float* __restrict__ bv, const float* __restrict__ bsk,
    const float* __restrict__ hemb, const float* __restrict__ We,
    const float* __restrict__ x,
    const float* __restrict__ fw1, const float* __restrict__ fb1,
    const float* __restrict__ fw2, const float* __restrict__ fb2,
    _Float16* __restrict__ WcatT, float* __restrict__ Wcat, float* __restrict__ bcat,
    _Float16* __restrict__ epth, _Float16* __restrict__ xh,
    _Float16* __restrict__ fw1h, _Float16* __restrict__ fw2Th,
    float* __restrict__ bfv, float* __restrict__ bzero, int Nn, int nb0) {
  __shared__ _Float16 tile[64][65];
  if (blockIdx.x >= nb0) {  // fw2 transpose+cast tail blocks (32 tiles)
    const int tb = blockIdx.x - nb0;
    const int l = tb >> 4, r2 = tb & 15;
    const int k0 = (r2 >> 1) << 6, j0 = (r2 & 1) << 6;
    const size_t base = (size_t)l * 65536;
    const int tid = threadIdx.x;
    for (int idx = tid; idx < 4096; idx += 256) {
      int rr = idx >> 6, cc = idx & 63;
      tile[rr][cc] = (_Float16)fw2[base + (size_t)(k0 + rr) * 128 + j0 + cc];
    }
    __syncthreads();
    for (int idx = tid; idx < 4096; idx += 256) {
      int rr = idx >> 6, cc = idx & 63;
      fw2Th[base + (size_t)(j0 + rr) * 512 + k0 + cc] = tile[cc][rr];
    }
    return;
  }
  int t = blockIdx.x * 256 + threadIdx.x;
  if (t < 256) {  // bfv[l][j]
    int l = t >> 7, j = t & 127;
    const float* b1 = fb1 + l * 512;
    const float* w2 = fw2 + (size_t)l * 65536 + j;
    float s0 = fb2[l * 128 + j], s1 = 0.f, s2 = 0.f, s3 = 0.f;
    for (int k = 0; k < 512; k += 4) {
      s0 = fmaf(b1[k], w2[(size_t)k * 128], s0);
      s1 = fmaf(b1[k + 1], w2[(size_t)(k + 1) * 128], s1);
      s2 = fmaf(b1[k + 2], w2[(size_t)(k + 2) * 128], s2);
      s3 = fmaf(b1[k + 3], w2[(size_t)(k + 3) * 128], s3);
    }
    bfv[t] = ((s0 + s1) + (s2 + s3));
    return;
  }
  t -= 256;
  if (t < 2560) {  // eproj
    int ty = t >> 8, col = t & 255;
    float s0 = 0.f, s1 = 0.f, s2 = 0.f, s3 = 0.f;
    const float* hr = hemb + ty * 128;
    for (int c = 0; c < 128; c += 4) {
      s0 = fmaf(hr[c], We[c * 256 + col], s0);
      s1 = fmaf(hr[c + 1], We[(c + 1) * 256 + col], s1);
      s2 = fmaf(hr[c + 2], We[(c + 2) * 256 + col], s2);
      s3 = fmaf(hr[c + 3], We[(c + 3) * 256 + col], s3);
    }
    epth[t] = (_Float16)((s0 + s1) + (s2 + s3));
    return;
  }
  t -= 2560;
  if (t < 114688) {  // WcatT f16 [896][128] + Wcat f32 [128][896]
    int n = t >> 7, k = t & 127;
    float v;
    if (n < 256) v = Wq[k * 256 + n];
    else if (n < 512) v = Wk[k * 256 + (n - 256)];
    else if (n < 768) v = Wv[k * 256 + (n - 512)];
    else v = Wsk[k * 128 + (n - 768)];
    WcatT[t] = (_Float16)v;
    Wcat[k * 896 + n] = v;
    return;
  }
  t -= 114688;
  if (t < 896) {
    float v;
    if (t < 256) v = bq[t];
    else if (t < 512) v = bk[t - 256];
    else if (t < 768) v = bv[t - 512];
    else v = bsk[t - 768];
    bcat[t] = v;
    return;
  }
  t -= 896;
  if (t < 1024) { bzero[t] = 0.f; return; }
  t -= 1024;
  if (t < 16384) {  // fw1 cast
    float4 v0 = *reinterpret_cast<const float4*>(fw1 + (size_t)t * 8);
    float4 v1 = *reinterpret_cast<const float4*>(fw1 + (size_t)t * 8 + 4);
    f16x8 o;
    o[0] = (_Float16)v0.x; o[1] = (_Float16)v0.y; o[2] = (_Float16)v0.z; o[3] = (_Float16)v0.w;
    o[4] = (_Float16)v1.x; o[5] = (_Float16)v1.y; o[6] = (_Float16)v1.z; o[7] = (_Float16)v1.w;
    *reinterpret_cast<f16x8*>(fw1h + (size_t)t * 8) = o;
    return;
  }
  t -= 16384;
  if (t < Nn * 16) {  // cast x -> f16
    float4 v0 = *reinterpret_cast<const float4*>(x + (size_t)t * 8);
    float4 v1 = *reinterpret_cast<const float4*>(x + (size_t)t * 8 + 4);
    f16x8 o;
    o[0] = (_Float16)v0.x; o[1] = (_Float16)v0.y; o[2] = (_Float16)v0.z; o[3] = (_Float16)v0.w;
    o[4] = (_Float16)v1.x; o[5] = (_Float16)v1.y; o[6] = (_Float16)v1.z; o[7] = (_Float16)v1.w;
    *reinterpret_cast<f16x8*>(xh + (size_t)t * 8) = o;
  }
}

// ---------------- pp_bmid: bmid = [bfv0 | bfv0@Wcat + bcat] ----------------
__global__ __launch_bounds__(256) void pp_bmid(const float* __restrict__ bfv,
                                               const float* __restrict__ Wcat,
                                               const float* __restrict__ bcat,
                                               float* __restrict__ bmid) {
  int t = blockIdx.x * 256 + threadIdx.x;
  if (t >= 1024) return;
  if (t < 128) { bmid[t] = bfv[t]; return; }
  int n = t - 128;
  float s0 = bcat[n], s1 = 0.f, s2 = 0.f, s3 = 0.f;
  for (int c = 0; c < 128; c += 4) {
    s0 = fmaf(bfv[c], Wcat[c * 896 + n], s0);
    s1 = fmaf(bfv[c + 1], Wcat[(c + 1) * 896 + n], s1);
    s2 = fmaf(bfv[c + 2], Wcat[(c + 2) * 896 + n], s2);
    s3 = fmaf(bfv[c + 3], Wcat[(c + 3) * 896 + n], s3);
  }
  bmid[t] = ((s0 + s1) + (s2 + s3));
}

// ---------------- Wf[z] = fw1h[z] @ fw2Th[z]^T  (grid.z=2) -------------
__global__ __launch_bounds__(256) void wf_gemm(const _Float16* __restrict__ fw1h,
                                               const _Float16* __restrict__ fw2Th,
                                               float* __restrict__ Wf,
                                               _Float16* __restrict__ Wfh,
                                               _Float16* __restrict__ BtMid0) {
  const int z = blockIdx.z;
  const _Float16* A = fw1h + z * 65536;
  const _Float16* Bt = fw2Th + z * 65536;
  const int tid = threadIdx.x;
  const int wid = tid >> 6, lane = tid & 63;
  const int wr = wid >> 1, wc = wid & 1;
  const int il = lane & 15, g = lane >> 4;
  const int row0 = wr * 64, col0 = wc * 64;
  const _Float16* Ap = A + (size_t)(row0 + il) * 512 + 8 * g;
  const _Float16* Bp = Bt + (size_t)(col0 + il) * 512 + 8 * g;
  f32x4 acc[4][4];
#pragma unroll
  for (int a = 0; a < 4; ++a)
#pragma unroll
    for (int b = 0; b < 4; ++b) acc[a][b] = (f32x4){0.f, 0.f, 0.f, 0.f};
  for (int k0 = 0; k0 < 512; k0 += 32) {
    f16x8 af[4], bf[4];
#pragma unroll
    for (int f = 0; f < 4; ++f) {
      af[f] = *reinterpret_cast<const f16x8*>(Ap + (size_t)(f * 16) * 512 + k0);
      bf[f] = *reinterpret_cast<const f16x8*>(Bp + (size_t)(f * 16) * 512 + k0);
    }
#pragma unroll
    for (int fi = 0; fi < 4; ++fi)
#pragma unroll
      for (int fj = 0; fj < 4; ++fj)
        acc[fi][fj] = __builtin_amdgcn_mfma_f32_16x16x32_f16(af[fi], bf[fj], acc[fi][fj], 0, 0, 0);
  }
#pragma unroll
  for (int fj = 0; fj < 4; ++fj) {
    const int col = col0 + fj * 16 + il;
#pragma unroll
    for (int fi = 0; fi < 4; ++fi) {
#pragma unroll
      for (int i = 0; i < 4; ++i) {
        const int row = row0 + fi * 16 + g * 4 + i;
        const float v = acc[fi][fj][i];
        Wf[z * 16384 + row * 128 + col] = v;
        if (z == 0) {
          Wfh[row * 128 + col] = (_Float16)v;
          BtMid0[col * 128 + row] = (_Float16)v;
        }
      }
    }
  }
}

// ---------------- MFMA f16 GEMM: C = A[M,K] @ Bt[N,K]^T + bias ----------------
template <bool HAS_CFH, bool HAS_CH, bool HAS_CHT>
__global__ __launch_bounds__(256) void gemm_tn_f16(const _Float16* __restrict__ A,
                                                   const _Float16* __restrict__ Bt,
                                                   const float* __restrict__ bias,
                                                   _Float16* __restrict__ Cfh, int NF,
                                                   _Float16* __restrict__ Ch, int choff, int ldh,
                                                   _Float16* __restrict__ ChT, int ldt,
                                                   int M, int N, int K) {
  const int tid = threadIdx.x;
  const int wid = tid >> 6, lane = tid & 63;
  const int wr = wid >> 1, wc = wid & 1;
  const int il = lane & 15, g = lane >> 4;
  const int row0 = blockIdx.y * 128 + wr * 64;
  const int col0 = blockIdx.x * 128 + wc * 64;
  const _Float16* Ap = A + (size_t)(row0 + il) * K + 8 * g;
  const _Float16* Bp = Bt + (size_t)(col0 + il) * K + 8 * g;
  f32x4 acc[4][4];
#pragma unroll
  for (int a = 0; a < 4; ++a)
#pragma unroll
    for (int b = 0; b < 4; ++b) acc[a][b] = (f32x4){0.f, 0.f, 0.f, 0.f};
  for (int k0 = 0; k0 < K; k0 += 32) {
    f16x8 af[4], bf[4];
#pragma unroll
    for (int f = 0; f < 4; ++f) {
      af[f] = *reinterpret_cast<const f16x8*>(Ap + (size_t)(f * 16) * K + k0);
      bf[f] = *reinterpret_cast<const f16x8*>(Bp + (size_t)(f * 16) * K + k0);
    }
#pragma unroll
    for (int fi = 0; fi < 4; ++fi)
#pragma unroll
      for (int fj = 0; fj < 4; ++fj)
        acc[fi][fj] = __builtin_amdgcn_mfma_f32_16x16x32_f16(af[fi], bf[fj], acc[fi][fj], 0, 0, 0);
  }
#pragma unroll
  for (int fj = 0; fj < 4; ++fj) {
    const int col = col0 + fj * 16 + il;
    const float b = bias[col];
#pragma unroll
    for (int fi = 0; fi < 4; ++fi) {
#pragma unroll
      for (int i = 0; i < 4; ++i) {
        const int row = row0 + fi * 16 + g * 4 + i;
        const float v = acc[fi][fj][i] + b;
        if constexpr (HAS_CFH) { if (col < NF) Cfh[(size_t)row * NF + col] = (_Float16)v; }
        if constexpr (HAS_CH) { if (col >= choff) Ch[(size_t)row * ldh + (col - choff)] = (_Float16)v; }
        if constexpr (HAS_CHT) { ChT[(size_t)col * ldt + row] = (_Float16)v; }
      }
    }
  }
}

// ---------------- fused per-node attention: SINGLE-PASS online softmax -------
// One wave per node (degree-sorted); 32 lanes per edge, 2 edge slots, prefetch
// depth 2. Defer-max (THR=8): rescale fires ~once per node (logits are tiny).
// K and V loads issue together (2x memory-level parallelism); no LDS logit
// staging, no chunk machinery.
__global__ __launch_bounds__(256) void node_attn_ln_kernel(
    const _Float16* __restrict__ QKVSh, const _Float16* __restrict__ epth,
    const _Float16* __restrict__ hpre,
    const int* __restrict__ offs, const unsigned* __restrict__ epk,
    const int* __restrict__ order,
    const float* __restrict__ gamma, const float* __restrict__ beta,
    _Float16* __restrict__ hlnh, int Nn) {
  __shared__ float sqe[4][2][10];
  __shared__ __align__(16) _Float16 elds[2560];
  const int tid = threadIdx.x;
  for (int t = tid; t < 1280; t += 256)
    reinterpret_cast<unsigned*>(elds)[t] = reinterpret_cast<const unsigned*>(epth)[t];
  __syncthreads();
  const int w = tid >> 6, lane = tid & 63;
  const int i = order[blockIdx.x * 4 + w];
  const int sub = lane >> 5;
  const int r = lane & 31;
  const int half = r >> 4;
  const int co = r << 3;
  const float scale = 0.08838834764831845f;  // 1/sqrt(128)
  f16x8 qh = *reinterpret_cast<const f16x8*>(QKVSh + (size_t)i * QW + co);
  const f16x2* q2 = reinterpret_cast<const f16x2*>(&qh);
  // prologue: qe[head][ty] = scale * (q_head . e_ty)
#pragma unroll
  for (int ty = 0; ty < 10; ++ty) {
    f16x8 ev = *reinterpret_cast<const f16x8*>(elds + (ty << 8) + co);
    const f16x2* e2 = reinterpret_cast<const f16x2*>(&ev);
    float s = 0.f;
#pragma unroll
    for (int p2 = 0; p2 < 4; ++p2) s = fdot2f(q2[p2], e2[p2], s);
    s += __shfl_xor(s, 1); s += __shfl_xor(s, 2);
    s += __shfl_xor(s, 4); s += __shfl_xor(s, 8);
    if (lane < 32 && (r & 15) == 0) sqe[w][half][ty] = s * scale;
  }
  __threadfence_block();
  float m_me = -1e30f, s_me = 0.f;
  float acc[8] = {0.f};
  const int ebeg = offs[i], eend = offs[i + 1];
  if (ebeg < eend) {
    const int last = eend - 1;
    unsigned pk0 = epk[min(ebeg + sub, last)];
    unsigned pk1 = epk[min(ebeg + 2 + sub, last)];
    const _Float16* r0p = QKVSh + (size_t)(pk0 & 0x3FFFF) * QW;
    const _Float16* r1p = QKVSh + (size_t)(pk1 & 0x3FFFF) * QW;
    f16x8 kv0 = *reinterpret_cast<const f16x8*>(r0p + 256 + co);
    f16x8 vv0 = *reinterpret_cast<const f16x8*>(r0p + 512 + co);
    f16x8 kv1 = *reinterpret_cast<const f16x8*>(r1p + 256 + co);
    f16x8 vv1 = *reinterpret_cast<const f16x8*>(r1p + 512 + co);
    for (int j = ebeg; j < eend; j += 2) {
      f16x8 kc = kv0, vc = vv0;
      const unsigned pkc = pk0;
      kv0 = kv1; vv0 = vv1; pk0 = pk1;
      pk1 = epk[min(j + 4 + sub, last)];
      const _Float16* rp = QKVSh + (size_t)(pk1 & 0x3FFFF) * QW;
      kv1 = *reinterpret_cast<const f16x8*>(rp + 256 + co);
      vv1 = *reinterpret_cast<const f16x8*>(rp + 512 + co);
      const int tyc = pkc >> 18;
      const f16x2* k2 = reinterpret_cast<const f16x2*>(&kc);
      float d = 0.f;
#pragma unroll
      for (int p2 = 0; p2 < 4; ++p2) d = fdot2f(q2[p2], k2[p2], d);
      d += __shfl_xor(d, 1); d += __shfl_xor(d, 2);
      d += __shfl_xor(d, 4); d += __shfl_xor(d, 8);
      d = d * scale + sqe[w][half][tyc];
      float e;
      if (d > m_me + 8.f) {  // defer-max: fires ~once per node
        const float rr = __expf(m_me - d);
        s_me *= rr;
#pragma unroll
        for (int t = 0; t < 8; ++t) acc[t] *= rr;
        m_me = d;
        e = 1.f;
      } else {
        e = __expf(d - m_me);
      }
      if (j + sub >= eend) e = 0.f;  // odd-tail mask
      s_me += e;
      f16x8 ec = *reinterpret_cast<const f16x8*>(elds + (tyc << 8) + co);
      f16x8 ve = vc + ec;
#pragma unroll
      for (int t = 0; t < 8; ++t) acc[t] = fmaf((float)ve[t], e, acc[t]);
    }
  }
  // merge the two edge slots (lane^32 holds same (half, co))
  const float mo = __shfl_xor(m_me, 32);
  const float so = __shfl_xor(s_me, 32);
  const float mf = fmaxf(m_me, mo);
  const float sc_me = __expf(m_me - mf);
  const float sc_o = __expf(mo - mf);
  const float s_tot = s_me * sc_me + so * sc_o;
  const float invme = 1.f / (s_tot + 1e-16f);
  float g[8];
#pragma unroll
  for (int t = 0; t < 8; ++t) {
    const float ao = __shfl_xor(acc[t], 32);
    const float a = (acc[t] * sc_me + ao * sc_o) * invme;
    g[t] = 0.5f * (a + __shfl_xor(a, 16));  // head mean
  }
  const int cm = (r & 15) << 3;
  f16x8 sk = *reinterpret_cast<const f16x8*>(QKVSh + (size_t)i * QW + 768 + cm);
  f16x8 pr = *reinterpret_cast<const f16x8*>(hpre + (size_t)i * DD + cm);
  float xv[8];
#pragma unroll
  for (int t = 0; t < 8; ++t) xv[t] = g[t] + (float)sk[t] + (float)pr[t];
  float sm = 0.f;
#pragma unroll
  for (int t = 0; t < 8; ++t) sm += xv[t];
  sm += __shfl_xor(sm, 1); sm += __shfl_xor(sm, 2);
  sm += __shfl_xor(sm, 4); sm += __shfl_xor(sm, 8);
  const float mu = sm * (1.f / 128.f);
  float dx[8], vvs = 0.f;
#pragma unroll
  for (int t = 0; t < 8; ++t) { dx[t] = xv[t] - mu; vvs += dx[t] * dx[t]; }
  vvs += __shfl_xor(vvs, 1); vvs += __shfl_xor(vvs, 2);
  vvs += __shfl_xor(vvs, 4); vvs += __shfl_xor(vvs, 8);
  const float rstd = rsqrtf(vvs * (1.f / 128.f) + 1e-6f);
  if (lane < 16) {
    float4 gm0 = *reinterpret_cast<const float4*>(gamma + cm);
    float4 gm1 = *reinterpret_cast<const float4*>(gamma + cm + 4);
    float4 bt0 = *reinterpret_cast<const float4*>(beta + cm);
    float4 bt1 = *reinterpret_cast<const float4*>(beta + cm + 4);
    f16x8 o;
    o[0] = (_Float16)(dx[0] * rstd * gm0.x + bt0.x);
    o[1] = (_Float16)(dx[1] * rstd * gm0.y + bt0.y);
    o[2] = (_Float16)(dx[2] * rstd * gm0.z + bt0.z);
    o[3] = (_Float16)(dx[3] * rstd * gm0.w + bt0.w);
    o[4] = (_Float16)(dx[4] * rstd * gm1.x + bt1.x);
    o[5] = (_Float16)(dx[5] * rstd * gm1.y + bt1.y);
    o[6] = (_Float16)(dx[6] * rstd * gm1.z + bt1.z);
    o[7] = (_Float16)(dx[7] * rstd * gm1.w + bt1.w);
    *reinterpret_cast<f16x8*>(hlnh + (size_t)i * DD + cm) = o;
  }
}

// ---------------- final: gather mask rows of hln1, apply layer-1 fused FFN ----------------
__global__ __launch_bounds__(128) void final_kernel(const _Float16* __restrict__ hlnh1,
                                                    const float* __restrict__ Wf,
                                                    const float* __restrict__ bfv,
                                                    const int* __restrict__ midx,
                                                    float* __restrict__ out) {
  __shared__ float rowv[128];
  const int b = blockIdx.x, j = threadIdx.x;
  const int row = midx[b];
  rowv[j] = (float)hlnh1[(size_t)row * DD + j];
  __syncthreads();
  const float* w1 = Wf + 16384 + j;
  float s = bfv[128 + j];
#pragma unroll 4
  for (int c = 0; c < 128; ++c) s = fmaf(rowv[c], w1[c * 128], s);
  out[b * DD + j] = s;
}

extern "C" void kernel_launch(void* const* d_in, const int* in_sizes, int n_in,
                              void* d_out, int out_size, void* d_ws, size_t ws_size,
                              hipStream_t stream) {
  const float* x    = (const float*)d_in[0];
  const float* hemb = (const float*)d_in[1];
  const float* Wq   = (const float*)d_in[2];
  const float* bq   = (const float*)d_in[3];
  const float* Wk   = (const float*)d_in[4];
  const float* bk   = (const float*)d_in[5];
  const float* Wv   = (const float*)d_in[6];
  const float* bv   = (const float*)d_in[7];
  const float* We   = (const float*)d_in[8];
  const float* Wsk  = (const float*)d_in[9];
  const float* bsk  = (const float*)d_in[10];
  const float* lng  = (const float*)d_in[11];
  const float* lnb  = (const float*)d_in[12];
  const float* fw1  = (const float*)d_in[13];
  const float* fb1  = (const float*)d_in[14];
  const float* fw2  = (const float*)d_in[15];
  const float* fb2  = (const float*)d_in[16];
  const int* eidx   = (const int*)d_in[17];
  const int* etyp   = (const int*)d_in[18];
  const int* midx   = (const int*)d_in[19];

  const int Nn = in_sizes[0] / DD;     // 16000
  const int E = in_sizes[18];          // 256000

  const int* esrc = eidx;
  const int* edst = eidx + E;

  char* p = (char*)d_ws;
  auto alloc = [&](size_t bytes) -> void* {
    void* r = (void*)p;
    p += (bytes + 255) & ~(size_t)255;
    return r;
  };
  _Float16* QKVSh = (_Float16*)alloc((size_t)Nn * QW * 2);
  _Float16* xh    = (_Float16*)alloc((size_t)Nn * DD * 2);
  _Float16* hln0  = (_Float16*)alloc((size_t)Nn * DD * 2);
  _Float16* hln1  = (_Float16*)alloc((size_t)Nn * DD * 2);
  _Float16* h1h   = (_Float16*)alloc((size_t)Nn * DD * 2);
  _Float16* WcatT = (_Float16*)alloc((size_t)QW * DD * 2);
  float*    Wcat  = (float*)alloc((size_t)DD * QW * 4);
  float*    bcat  = (float*)alloc(QW * 4);
  _Float16* epth  = (_Float16*)alloc(2560 * 2);
  _Float16* fw1h  = (_Float16*)alloc((size_t)2 * DD * 512 * 2);
  _Float16* fw2Th = (_Float16*)alloc((size_t)2 * DD * 512 * 2);
  float*    Wf    = (float*)alloc(2 * 128 * 128 * 4);
  _Float16* Wfh   = (_Float16*)alloc(128 * 128 * 2);
  float*    bfv   = (float*)alloc(256 * 4);
  float*    bzero = (float*)alloc(1024 * 4);
  _Float16* BtMid = (_Float16*)alloc((size_t)1024 * 128 * 2);
  float*    bmid  = (float*)alloc(1024 * 4);
  int* offs   = (int*)alloc((size_t)(Nn + 1) * 4);
  int* bbase  = (int*)alloc((NB + 1) * 4);
  int* bcursor= (int*)alloc((NB + 1) * 4);
  int* dcur   = (int*)alloc(64 * 4);
  int* order  = (int*)alloc((size_t)Nn * 4);
  const int nsblk = (E + 2047) / 2048;
  int* bparts = (int*)alloc((size_t)nsblk * 128 * 4);
  int* dparts = (int*)alloc((size_t)NB * 64 * 4);
  unsigned* ebuf = (unsigned*)alloc((size_t)E * 4);
  unsigned* epk  = (unsigned*)alloc((size_t)E * 4);

  // CSR build (no memsets: partial histograms)
  csr_count<<<nsblk, 256, 0, stream>>>(edst, bparts, E);
  csr_scan<<<1, 128, 0, stream>>>(bparts, nsblk, bbase, bcursor, offs, E, Nn);
  csr_scatter<<<nsblk, 256, 0, stream>>>(edst, esrc, etyp, bcursor, ebuf, E);
  csr_fine<<<NB, 256, 0, stream>>>(ebuf, bbase, epk, offs, dparts);
  deg_scan<<<1, 64, 0, stream>>>(dparts, NB, dcur);
  deg_order<<<(Nn + 255) / 256, 256, 0, stream>>>(offs, dcur, order, Nn);

  // Precompute (pp_cast includes fw2 transpose tail blocks)
  const int pc_threads = 256 + 2560 + 114688 + 896 + 1024 + 16384 + Nn * 16;
  const int nb0 = (pc_threads + 255) / 256;
  pp_cast<<<nb0 + 32, 256, 0, stream>>>(
      Wq, Wk, Wv, Wsk, bq, bk, bv, bsk, hemb, We, x, fw1, fb1, fw2, fb2,
      WcatT, Wcat, bcat, epth, xh, fw1h, fw2Th, bfv, bzero, Nn, nb0);
  pp_bmid<<<4, 256, 0, stream>>>(bfv, Wcat, bcat, bmid);
  wf_gemm<<<dim3(1, 1, 2), 256, 0, stream>>>(fw1h, fw2Th, Wf, Wfh, BtMid);
  // BtMid rows 128..1023 = (Wf0 @ Wcat)^T
  gemm_tn_f16<false, false, true><<<dim3(7, 1), 256, 0, stream>>>(
      Wfh, WcatT, bzero, nullptr, 0, nullptr, 0, 0, BtMid + 16384, 128, 128, 896, 128);

  // Layer 0: QKVS0 = xh @ Wcat + bcat
  gemm_tn_f16<false, true, false><<<dim3(QW / 128, Nn / 128), 256, 0, stream>>>(
      xh, WcatT, bcat, nullptr, 0, QKVSh, 0, QW, nullptr, 0, Nn, QW, DD);
  node_attn_ln_kernel<<<Nn / 4, 256, 0, stream>>>(QKVSh, epth, xh, offs, epk, order,
                                                  lng, lnb, hln0, Nn);
  // Fused: [h1h (f16) | QKVS1 (f16)] = hln0 @ [Wf0 | Wf0@Wcat] + bmid
  gemm_tn_f16<true, true, false><<<dim3(1024 / 128, Nn / 128), 256, 0, stream>>>(
      hln0, BtMid, bmid, h1h, 128, QKVSh, 128, QW, nullptr, 0, Nn, 1024, DD);
  node_attn_ln_kernel<<<Nn / 4, 256, 0, stream>>>(QKVSh, epth, h1h, offs, epk, order,
                                                  lng + DD, lnb + DD, hln1, Nn);
  final_kernel<<<64, 128, 0, stream>>>(hln1, Wf, bfv, midx, (float*)d_out);
}